// Round 9
// baseline (221.513 us; speedup 1.0000x reference)
//
#include <hip/hip_runtime.h>
#include <math.h>

#define B_ 2
#define T_ 1024
#define E_ 1024
#define H_ 16
#define D_ 64
#define M_ (B_*T_)
#define SPLANE 32768   // scal plane stride (32 bh * 1024 t)

typedef __bf16 bf16x8 __attribute__((ext_vector_type(8)));
typedef __bf16 bf16x4 __attribute__((ext_vector_type(4)));
typedef __bf16 bf16x2 __attribute__((ext_vector_type(2)));
typedef float f32x4 __attribute__((ext_vector_type(4)));

// swizzled LDS addressing: row-major [rows][128 bytes], byte ^= (row&7)<<4
__device__ __forceinline__ void* ldsp(__bf16* base, int row, int byte) {
  return (char*)base + row * 128 + (byte ^ ((row & 7) << 4));
}

__device__ __forceinline__ void gload_lds16(const void* g, void* l) {
  __builtin_amdgcn_global_load_lds((const __attribute__((address_space(1))) void*)g,
                                   (__attribute__((address_space(3))) void*)l, 16, 0, 0);
}

// quarter-layout helpers: nq(qt) = qt/4+1, off(qt) = qt + 2a(a-1) + a*(qt&3), a=qt>>2
__device__ __forceinline__ int qoff(int qt) {
  int a = qt >> 2, r = qt & 3;
  return qt + 2 * a * (a - 1) + a * r;
}

// ---------------- K-1: f32 -> bf16 conversions (x, Wqkv, Wout) ----------------
#define XV4 524288     // (2*1024*1024)/4
#define WQV4 786432    // (3072*1024)/4
#define WOV4 262144    // (1024*1024)/4
#define TOTV4 (XV4 + WQV4 + WOV4)
__global__ __launch_bounds__(256) void conv_kernel(
    const float* __restrict__ x, const float* __restrict__ Wqkv,
    const float* __restrict__ Wout,
    __bf16* __restrict__ xb, __bf16* __restrict__ Wqkvb, __bf16* __restrict__ Woutb) {
  for (size_t i = (size_t)blockIdx.x * blockDim.x + threadIdx.x; i < TOTV4;
       i += (size_t)gridDim.x * blockDim.x) {
    const float4* src; __bf16* dst; size_t off;
    if (i < XV4)            { src = (const float4*)x;    dst = xb;    off = i; }
    else if (i < XV4+WQV4)  { src = (const float4*)Wqkv; dst = Wqkvb; off = i - XV4; }
    else                    { src = (const float4*)Wout; dst = Woutb; off = i - XV4 - WQV4; }
    float4 val = src[off];
    bf16x4 o = {(__bf16)val.x, (__bf16)val.y, (__bf16)val.z, (__bf16)val.w};
    *(bf16x4*)(dst + off * 4) = o;
  }
}

// ---------------- K0: importance (spike) + alpha (f32 — sign decision!) ----------------
__global__ __launch_bounds__(256) void imp_alpha_kernel(
    const float* __restrict__ x,
    const float* __restrict__ Wimp, const float* __restrict__ bimp,
    const float* __restrict__ Walpha, const float* __restrict__ balpha,
    const float* __restrict__ thr_p,
    float* __restrict__ spike, float* __restrict__ alpha) {
  int m = blockIdx.x;
  int tid = threadIdx.x;           // one float4 per thread (1024/4 = 256)
  const float4* xr = (const float4*)(x + (size_t)m * E_);
  float4 xv = xr[tid];
  float part[17];
  {
    float4 wv = ((const float4*)Wimp)[tid];
    part[16] = xv.x * wv.x + xv.y * wv.y + xv.z * wv.z + xv.w * wv.w;
  }
#pragma unroll
  for (int h = 0; h < 16; ++h) {
    float4 wv = ((const float4*)(Walpha + (size_t)h * E_))[tid];
    part[h] = xv.x * wv.x + xv.y * wv.y + xv.z * wv.z + xv.w * wv.w;
  }
  __shared__ float red[17][4];
  int lane = tid & 63, wv_ = tid >> 6;
#pragma unroll
  for (int i = 0; i < 17; ++i) {
    float v = part[i];
    for (int off = 32; off > 0; off >>= 1) v += __shfl_down(v, off, 64);
    if (lane == 0) red[i][wv_] = v;
  }
  __syncthreads();
  if (tid < 17) {
    float v = red[tid][0] + red[tid][1] + red[tid][2] + red[tid][3];
    if (tid == 16) {
      float z = v + bimp[0];
      float sig = 1.f / (1.f + expf(-z));
      spike[m] = (sig > thr_p[0]) ? 1.f : 0.f;
    } else {
      float z = v + balpha[tid];
      float a = 1.f / (1.f + expf(-z));
      int b = m >> 10, t = m & (T_ - 1);
      alpha[((size_t)(b * H_ + tid)) * T_ + t] = a;
    }
  }
}

// ---------------- K1: QKV GEMM — bf16 MFMA, 128x128 tile ----------------
__global__ __launch_bounds__(256) void qkv_gemm_kernel(
    const __bf16* __restrict__ A, const __bf16* __restrict__ Bm,
    const float* __restrict__ bias,
    __bf16* __restrict__ q, __bf16* __restrict__ k, __bf16* __restrict__ v) {
  __shared__ __bf16 As[128 * 32];
  __shared__ __bf16 Bs[128 * 32];
  const int K = E_;
  int tid = threadIdx.x;
  int w = tid >> 6, lane = tid & 63, lr = lane & 15, g = lane >> 4;
  int m0 = blockIdx.y * 128, n0 = blockIdx.x * 128;
  int wr = (w >> 1) * 64, wc = (w & 1) * 64;

  int task0 = tid, task1 = tid + 256;
  int r0s = task0 >> 2, c0s = task0 & 3;
  int r1s = task1 >> 2, c1s = task1 & 3;
  const __bf16* gA0 = A + (size_t)(m0 + r0s) * K + c0s * 8;
  const __bf16* gA1 = A + (size_t)(m0 + r1s) * K + c1s * 8;
  const __bf16* gB0 = Bm + (size_t)(n0 + r0s) * K + c0s * 8;
  const __bf16* gB1 = Bm + (size_t)(n0 + r1s) * K + c1s * 8;
  __bf16* lA0 = As + task0 * 8;
  __bf16* lA1 = As + task1 * 8;
  __bf16* lB0 = Bs + task0 * 8;
  __bf16* lB1 = Bs + task1 * 8;

  f32x4 acc[4][4];
#pragma unroll
  for (int i = 0; i < 4; ++i)
#pragma unroll
    for (int j = 0; j < 4; ++j) acc[i][j] = (f32x4){0.f, 0.f, 0.f, 0.f};

  for (int k0 = 0; k0 < K; k0 += 32) {
    gload_lds16(gA0, lA0); gload_lds16(gA1, lA1);
    gload_lds16(gB0, lB0); gload_lds16(gB1, lB1);
    gA0 += 32; gA1 += 32; gB0 += 32; gB1 += 32;
    __syncthreads();
    bf16x8 af[4], bf[4];
#pragma unroll
    for (int i = 0; i < 4; ++i) af[i] = *(bf16x8*)&As[(wr + i * 16 + lr) * 32 + g * 8];
#pragma unroll
    for (int j = 0; j < 4; ++j) bf[j] = *(bf16x8*)&Bs[(wc + j * 16 + lr) * 32 + g * 8];
#pragma unroll
    for (int i = 0; i < 4; ++i)
#pragma unroll
      for (int j = 0; j < 4; ++j)
        acc[i][j] = __builtin_amdgcn_mfma_f32_16x16x32_bf16(af[i], bf[j], acc[i][j], 0, 0, 0);
    __syncthreads();
  }

#pragma unroll
  for (int i = 0; i < 4; ++i) {
#pragma unroll
    for (int r = 0; r < 4; ++r) {
      int m = m0 + wr + i * 16 + g * 4 + r;
      int b = m >> 10, t = m & (T_ - 1);
#pragma unroll
      for (int j = 0; j < 4; ++j) {
        int n = n0 + wc + j * 16 + lr;
        float val = acc[i][j][r] + bias[n];
        int comp = n >> 10, h = (n >> 6) & 15, d = n & 63;
        __bf16* dst = (comp == 0) ? q : ((comp == 1) ? k : v);
        dst[(((size_t)(b * H_ + h)) * T_ + t) * 64 + d] = (__bf16)val;
      }
    }
  }
}

// ---------------- K2: hyperboloid scalars A,B,C per row ----------------
__global__ __launch_bounds__(256) void scal_kernel(
    const __bf16* __restrict__ q, const __bf16* __restrict__ k,
    const float* __restrict__ qk_scale_p,
    float* __restrict__ scalq, float* __restrict__ scalk) {
  int wid = blockIdx.x * 4 + (threadIdx.x >> 6);
  int lane = threadIdx.x & 63;
  int is_k = wid >> 15;
  int row = wid & 32767;
  const __bf16* src = (is_k ? k : q) + (size_t)row * 64;
  float u = (float)src[lane];
  float nsq = u * u;
#pragma unroll
  for (int off = 32; off > 0; off >>= 1) nsq += __shfl_xor(nsq, off, 64);
  float norm = fmaxf(sqrtf(nsq), 1e-12f);
  float ss = 1.5f / (1.f + expf(-qk_scale_p[0]));
  float row0 = __shfl(u, 0, 64);
  float un0 = row0 / norm * ss;
  float mink = ss * ss - 2.f * un0 * un0;
  float nu = sqrtf(fmaxf(mink, 1e-8f));
  float sc = sinhf(nu) / nu;
  float Bv = sc * ss / norm;
  float Av = sqrtf(1.f + sc * sc * (ss * ss - un0 * un0));
  float Cv = Bv * row0;
  if (lane == 0) {
    float* dst = is_k ? scalk : scalq;
    dst[row] = Av;
    dst[SPLANE + row] = Bv;
    dst[2 * SPLANE + row] = Cv;
  }
}

// ---------------- K3: quarter-split staged dual-geometry flash attention ----------------
// grid 1280 = 32 bh x Σ_qt(qt/4+1)=40 quarter-blocks; each block <= 4 s-tiles.
// 5 blocks/CU resident, LDS 24KB, scal loads hoisted to tile prologue.
__global__ __launch_bounds__(256, 5) void attn_kernel(
    const __bf16* __restrict__ q, const __bf16* __restrict__ k, const __bf16* __restrict__ v,
    const float* __restrict__ scalq, const float* __restrict__ scalk,
    const float* __restrict__ alpha, const float* __restrict__ log_k,
    __bf16* __restrict__ pacc, float* __restrict__ pml) {
  __shared__ __bf16 k_s[64 * 64];
  __shared__ __bf16 vt_s[64 * 64];
  __shared__ __bf16 p_s[64 * 64];

  int bid = blockIdx.x;
  int bh = ((bid & 7) << 2) | ((bid >> 3) & 3);  // 4 bh per XCD (L2 locality)
  int l = bid >> 5;                              // 0..39 quarter-slot
  int qt = 0, ii = 0;
#pragma unroll
  for (int u = 0; u < 16; ++u) {
    int offu = qoff(u);
    int nqu = (u >> 2) + 1;
    if (l >= offu && l < offu + nqu) { qt = u; ii = l - offu; }
  }
  int h = bh & 15;
  int t0 = qt * 64;
  int s_beg = ii * 4;
  int s_end = min(ii * 4 + 4, qt + 1);

  int tid = threadIdx.x;
  int w = tid >> 6, lane = tid & 63;
  int lr = lane & 15, g = lane >> 4;
  int trow = w * 16;
  const size_t base = (size_t)bh * T_ * 64;

  // Q A-fragments straight from global (L2-hot)
  const __bf16* qrow = q + base + (size_t)(t0 + trow + lr) * 64;
  bf16x8 aq0 = *(const bf16x8*)(qrow + g * 8);
  bf16x8 aq1 = *(const bf16x8*)(qrow + 32 + g * 8);

  float curv = log1pf(expf(log_k[h])) + 1e-6f;
  float hc = 0.69314718056f / curv;        // ln2/curv (log2-domain)
  const float ec = 0.18033688f;            // 0.125 * log2(e)
  int tg[4]; float al[4], Aq[4], Bq[4], Cq[4];
#pragma unroll
  for (int r = 0; r < 4; ++r) {
    tg[r] = t0 + trow + g * 4 + r;
    int rowi = (bh << 10) + tg[r];
    al[r] = alpha[(size_t)bh * T_ + tg[r]];
    Aq[r] = scalq[rowi];
    Bq[r] = scalq[SPLANE + rowi];
    Cq[r] = scalq[2 * SPLANE + rowi];
  }

  float m_r[4] = {-1e30f, -1e30f, -1e30f, -1e30f};
  float l_r[4] = {0.f, 0.f, 0.f, 0.f};
  f32x4 acc[4];
#pragma unroll
  for (int n = 0; n < 4; ++n) acc[n] = (f32x4){0.f, 0.f, 0.f, 0.f};

  // staging task decomposition
  int task0 = tid, task1 = tid + 256;
  int row0s = task0 >> 3, cj0 = task0 & 7;
  int row1s = task1 >> 3, cj1 = task1 & 7;
  int s2 = tid & 31, dc = tid >> 5;        // V: 2 s-rows x 8 d each

  for (int st = s_beg; st < s_end; ++st) {
    int s0 = st * 64;
    bool diag = (st == qt);
    __syncthreads();
    // ---- hoisted per-column scalars (issue early; drained by staging barrier) ----
    float akv[4], bkv[4], ckv[4];
#pragma unroll
    for (int j = 0; j < 4; ++j) {
      int coli = (bh << 10) + s0 + j * 16 + lr;
      akv[j] = scalk[coli];
      bkv[j] = scalk[SPLANE + coli];
      ckv[j] = scalk[2 * SPLANE + coli];
    }
    // ---- stage K (b128) and V^T (packed b32 pairs) ----
    {
      bf16x8 a0 = *(const bf16x8*)(k + base + (size_t)(s0 + row0s) * 64 + cj0 * 8);
      bf16x8 a1 = *(const bf16x8*)(k + base + (size_t)(s0 + row1s) * 64 + cj1 * 8);
      *(bf16x8*)ldsp(k_s, row0s, cj0 * 16) = a0;
      *(bf16x8*)ldsp(k_s, row1s, cj1 * 16) = a1;
      bf16x8 v0 = *(const bf16x8*)(v + base + (size_t)(s0 + 2 * s2) * 64 + dc * 8);
      bf16x8 v1 = *(const bf16x8*)(v + base + (size_t)(s0 + 2 * s2 + 1) * 64 + dc * 8);
#pragma unroll
      for (int i = 0; i < 8; ++i) {
        bf16x2 pr = {v0[i], v1[i]};
        *(bf16x2*)ldsp(vt_s, dc * 8 + i, s2 * 4) = pr;
      }
    }
    __syncthreads();

    // ---- per-j: euclid MFMA + scalar-hyper blend (causal only on diagonal) ----
    float pv[4][4];
    float pmax[4] = {-1e30f, -1e30f, -1e30f, -1e30f};
#pragma unroll
    for (int j = 0; j < 4; ++j) {
      if (diag && (s0 + j * 16 > t0 + trow + 15)) {   // wave-uniform full mask
#pragma unroll
        for (int r = 0; r < 4; ++r) pv[j][r] = -1e30f;
        continue;
      }
      bf16x8 bk0 = *(bf16x8*)ldsp(k_s, j * 16 + lr, g * 16);
      bf16x8 bk1 = *(bf16x8*)ldsp(k_s, j * 16 + lr, 64 + g * 16);
      f32x4 z = {0.f, 0.f, 0.f, 0.f};
      z = __builtin_amdgcn_mfma_f32_16x16x32_bf16(aq0, bk0, z, 0, 0, 0);
      f32x4 se = __builtin_amdgcn_mfma_f32_16x16x32_bf16(aq1, bk1, z, 0, 0, 0);
      int sg = s0 + j * 16 + lr;
#pragma unroll
      for (int r = 0; r < 4; ++r) {
        float dot = se[r];
        float sc_e = dot * ec;
        float md = fmaf(-Bq[r] * bkv[j], dot, fmaf(Aq[r], akv[j], Cq[r] * ckv[j]));
        md = fmaxf(md, 1.0f + 1e-6f);
        float l2 = __log2f(md + sqrtf(fmaf(md, md, -1.f)));  // acosh, log2 units
        float t = fmaf(l2 * l2, hc, sc_e);
        float s = fmaf(-al[r], t, sc_e);                      // (1-a)e - a*h
        if (diag && sg > tg[r]) s = -1e30f;
        pv[j][r] = s;
        pmax[r] = fmaxf(pmax[r], s);
      }
    }
    // ---- online softmax (log2 domain) ----
#pragma unroll
    for (int r = 0; r < 4; ++r) {
      float mx = pmax[r];
      mx = fmaxf(mx, __shfl_xor(mx, 1, 64));
      mx = fmaxf(mx, __shfl_xor(mx, 2, 64));
      mx = fmaxf(mx, __shfl_xor(mx, 4, 64));
      mx = fmaxf(mx, __shfl_xor(mx, 8, 64));
      float mn = fmaxf(m_r[r], mx);
      float fac = exp2f(m_r[r] - mn);
      m_r[r] = mn;
      float ls = 0.f;
#pragma unroll
      for (int j = 0; j < 4; ++j) { pv[j][r] = exp2f(pv[j][r] - mn); ls += pv[j][r]; }
      ls += __shfl_xor(ls, 1, 64);
      ls += __shfl_xor(ls, 2, 64);
      ls += __shfl_xor(ls, 4, 64);
      ls += __shfl_xor(ls, 8, 64);
      l_r[r] = l_r[r] * fac + ls;
#pragma unroll
      for (int n = 0; n < 4; ++n) acc[n][r] *= fac;
    }
    // ---- P transpose through wave-private p_s rows (no barrier needed) ----
#pragma unroll
    for (int j = 0; j < 4; ++j)
#pragma unroll
      for (int r = 0; r < 4; ++r)
        *(__bf16*)ldsp(p_s, trow + g * 4 + r, (j * 16 + lr) * 2) = (__bf16)pv[j][r];
    bf16x8 ap0 = *(bf16x8*)ldsp(p_s, trow + lr, g * 16);
    bf16x8 ap1 = *(bf16x8*)ldsp(p_s, trow + lr, 64 + g * 16);
#pragma unroll
    for (int n = 0; n < 4; ++n) {
      bf16x8 bv0 = *(bf16x8*)ldsp(vt_s, n * 16 + lr, g * 16);
      bf16x8 bv1 = *(bf16x8*)ldsp(vt_s, n * 16 + lr, 64 + g * 16);
      acc[n] = __builtin_amdgcn_mfma_f32_16x16x32_bf16(ap0, bv0, acc[n], 0, 0, 0);
      acc[n] = __builtin_amdgcn_mfma_f32_16x16x32_bf16(ap1, bv1, acc[n], 0, 0, 0);
    }
  }

  // ---- write partials (merge kernel combines nq quarters) ----
  int pidx = ((bh * 40 + qoff(qt) + ii) << 2) | w;
  __bf16* pa = pacc + (size_t)pidx * 1024;
#pragma unroll
  for (int n = 0; n < 4; ++n)
#pragma unroll
    for (int r = 0; r < 4; ++r)
      pa[(g * 4 + r) * 64 + n * 16 + lr] = (__bf16)acc[n][r];
  if (lr == 0) {
#pragma unroll
    for (int r = 0; r < 4; ++r) {
      pml[(size_t)pidx * 32 + g * 4 + r] = m_r[r];
      pml[(size_t)pidx * 32 + 16 + g * 4 + r] = l_r[r];
    }
  }
}

// ---------------- K3b: merge nq quarters + spike gate -> yw (bf16) ----------------
__global__ __launch_bounds__(256) void merge_kernel(
    const __bf16* __restrict__ pacc, const float* __restrict__ pml,
    const float* __restrict__ spike, __bf16* __restrict__ yw) {
  int tid = threadIdx.x;
  int w = tid >> 6, lane = tid & 63;
  int wid = blockIdx.x * 4 + w;          // 0..2047
  int bh = wid & 31;
  int qt16 = wid >> 5;                   // 0..63 (16-row tile)
  int b = bh >> 4, h = bh & 15;
  int qt = qt16 >> 2, wsub = qt16 & 3;
  int nq = (qt >> 2) + 1;
  int offq = qoff(qt);
  int pp[4];
#pragma unroll
  for (int i = 0; i < 4; ++i)
    pp[i] = ((bh * 40 + offq + min(i, nq - 1)) << 2) | wsub;

  for (int row = 0; row < 16; ++row) {
    float mm = -1e30f;
    float mv[4];
#pragma unroll
    for (int i = 0; i < 4; ++i) {
      mv[i] = (i < nq) ? pml[(size_t)pp[i] * 32 + row] : -1e30f;
      mm = fmaxf(mm, mv[i]);
    }
    float lsum = 0.f, val = 0.f;
#pragma unroll
    for (int i = 0; i < 4; ++i) {
      if (i < nq) {
        float f = exp2f(mv[i] - mm);
        lsum += pml[(size_t)pp[i] * 32 + 16 + row] * f;
        val += (float)pacc[(size_t)pp[i] * 1024 + row * 64 + lane] * f;
      }
    }
    int t = qt16 * 16 + row;
    float iv = spike[(size_t)b * T_ + t] / lsum;
    yw[(size_t)(b * T_ + t) * E_ + h * 64 + lane] = (__bf16)(val * iv);
  }
}

// ---------------- K4: output projection — bf16 MFMA, f32 out ----------------
__global__ __launch_bounds__(256) void out_gemm_kernel(
    const __bf16* __restrict__ A, const __bf16* __restrict__ Bm,
    const float* __restrict__ bias, float* __restrict__ outp) {
  __shared__ __bf16 As[128 * 32];
  __shared__ __bf16 Bs[128 * 32];
  const int K = E_;
  int tid = threadIdx.x;
  int w = tid >> 6, lane = tid & 63, lr = lane & 15, g = lane >> 4;
  int m0 = blockIdx.y * 128, n0 = blockIdx.x * 128;
  int wr = (w >> 1) * 64, wc = (w & 1) * 64;

  int task0 = tid, task1 = tid + 256;
  int r0s = task0 >> 2, c0s = task0 & 3;
  int r1s = task1 >> 2, c1s = task1 & 3;
  const __bf16* gA0 = A + (size_t)(m0 + r0s) * K + c0s * 8;
  const __bf16* gA1 = A + (size_t)(m0 + r1s) * K + c1s * 8;
  const __bf16* gB0 = Bm + (size_t)(n0 + r0s) * K + c0s * 8;
  const __bf16* gB1 = Bm + (size_t)(n0 + r1s) * K + c1s * 8;
  __bf16* lA0 = As + task0 * 8;
  __bf16* lA1 = As + task1 * 8;
  __bf16* lB0 = Bs + task0 * 8;
  __bf16* lB1 = Bs + task1 * 8;

  f32x4 acc[4][4];
#pragma unroll
  for (int i = 0; i < 4; ++i)
#pragma unroll
    for (int j = 0; j < 4; ++j) acc[i][j] = (f32x4){0.f, 0.f, 0.f, 0.f};

  for (int k0 = 0; k0 < K; k0 += 32) {
    gload_lds16(gA0, lA0); gload_lds16(gA1, lA1);
    gload_lds16(gB0, lB0); gload_lds16(gB1, lB1);
    gA0 += 32; gA1 += 32; gB0 += 32; gB1 += 32;
    __syncthreads();
    bf16x8 af[4], bf[4];
#pragma unroll
    for (int i = 0; i < 4; ++i) af[i] = *(bf16x8*)&As[(wr + i * 16 + lr) * 32 + g * 8];
#pragma unroll
    for (int j = 0; j < 4; ++j) bf[j] = *(bf16x8*)&Bs[(wc + j * 16 + lr) * 32 + g * 8];
#pragma unroll
    for (int i = 0; i < 4; ++i)
#pragma unroll
      for (int j = 0; j < 4; ++j)
        acc[i][j] = __builtin_amdgcn_mfma_f32_16x16x32_bf16(af[i], bf[j], acc[i][j], 0, 0, 0);
    __syncthreads();
  }

#pragma unroll
  for (int i = 0; i < 4; ++i) {
#pragma unroll
    for (int r = 0; r < 4; ++r) {
      int m = m0 + wr + i * 16 + g * 4 + r;
#pragma unroll
      for (int j = 0; j < 4; ++j) {
        int n = n0 + wc + j * 16 + lr;
        outp[(size_t)m * E_ + n] = acc[i][j][r] + bias[n];
      }
    }
  }
}

extern "C" void kernel_launch(void* const* d_in, const int* in_sizes, int n_in,
                              void* d_out, int out_size, void* d_ws, size_t ws_size,
                              hipStream_t stream) {
  const float* x      = (const float*)d_in[0];
  const float* Wqkv   = (const float*)d_in[1];
  const float* bqkv   = (const float*)d_in[2];
  const float* Wout   = (const float*)d_in[3];
  const float* bout   = (const float*)d_in[4];
  const float* Wimp   = (const float*)d_in[5];
  const float* bimp   = (const float*)d_in[6];
  const float* Walpha = (const float*)d_in[7];
  const float* balpha = (const float*)d_in[8];
  const float* thr    = (const float*)d_in[9];
  const float* log_k  = (const float*)d_in[10];
  const float* qk_sc  = (const float*)d_in[11];
  float* out = (float*)d_out;

  char* ws = (char*)d_ws;
  size_t off = 0;
  auto alloc = [&](size_t bytes) -> void* {
    void* p = (void*)(ws + off);
    off += (bytes + 255) & ~(size_t)255;
    return p;
  };
  const size_t qkv_elems = (size_t)B_ * H_ * T_ * D_;
  __bf16* xb    = (__bf16*)alloc((size_t)M_ * E_ * 2);      // dead after qkv_gemm
  __bf16* Wqkvb = (__bf16*)alloc((size_t)3 * E_ * E_ * 2);  // dead after qkv_gemm
  __bf16* Woutb = (__bf16*)alloc((size_t)E_ * E_ * 2);
  __bf16* q   = (__bf16*)alloc(qkv_elems * 2);
  __bf16* k   = (__bf16*)alloc(qkv_elems * 2);
  __bf16* v   = (__bf16*)alloc(qkv_elems * 2);
  __bf16* yw  = (__bf16*)alloc((size_t)M_ * E_ * 2);
  float* alphaw = (float*)alloc((size_t)B_ * H_ * T_ * sizeof(float));
  float* spikew = (float*)alloc((size_t)M_ * sizeof(float));
  float* pml    = (float*)alloc((size_t)5120 * 32 * sizeof(float));
  float* scalq  = (float*)alloc((size_t)3 * SPLANE * sizeof(float));
  float* scalk  = (float*)alloc((size_t)3 * SPLANE * sizeof(float));
  // pacc: 5120 partials x 1024 bf16 = 10,485,760 B == xb(4MB)+Wqkvb(6MB) alias
  __bf16* pacc = (__bf16*)ws;

  conv_kernel<<<1024, 256, 0, stream>>>(x, Wqkv, Wout, xb, Wqkvb, Woutb);
  imp_alpha_kernel<<<M_, 256, 0, stream>>>(x, Wimp, bimp, Walpha, balpha, thr,
                                           spikew, alphaw);
  qkv_gemm_kernel<<<dim3(24, 16), 256, 0, stream>>>(xb, Wqkvb, bqkv, q, k, v);
  scal_kernel<<<(2 * B_ * H_ * T_) / 4, 256, 0, stream>>>(q, k, qk_sc, scalq, scalk);
  attn_kernel<<<1280, 256, 0, stream>>>(q, k, v, scalq, scalk, alphaw, log_k,
                                        pacc, pml);
  merge_kernel<<<512, 256, 0, stream>>>(pacc, pml, spikew, yw);
  out_gemm_kernel<<<dim3(8, 16), 256, 0, stream>>>(yw, Woutb, bout, out);
}

// Round 10
// 163.325 us; speedup vs baseline: 1.3563x; 1.3563x over previous
//
#include <hip/hip_runtime.h>
#include <math.h>

#define B_ 2
#define T_ 1024
#define E_ 1024
#define H_ 16
#define D_ 64
#define M_ (B_*T_)
#define SPLANE 32768   // scal plane stride (32 bh * 1024 t)

typedef __bf16 bf16x8 __attribute__((ext_vector_type(8)));
typedef __bf16 bf16x4 __attribute__((ext_vector_type(4)));
typedef __bf16 bf16x2 __attribute__((ext_vector_type(2)));
typedef float f32x4 __attribute__((ext_vector_type(4)));

// swizzled LDS addressing: row-major [rows][128 bytes], byte ^= (row&7)<<4
__device__ __forceinline__ void* ldsp(__bf16* base, int row, int byte) {
  return (char*)base + row * 128 + (byte ^ ((row & 7) << 4));
}

__device__ __forceinline__ void gload_lds16(const void* g, void* l) {
  __builtin_amdgcn_global_load_lds((const __attribute__((address_space(1))) void*)g,
                                   (__attribute__((address_space(3))) void*)l, 16, 0, 0);
}

// quarter-layout helpers: nq(qt) = qt/4+1, off(qt) = qt + 2a(a-1) + a*(qt&3), a=qt>>2
__device__ __forceinline__ int qoff(int qt) {
  int a = qt >> 2, r = qt & 3;
  return qt + 2 * a * (a - 1) + a * r;
}

// ---------------- K-1: f32 -> bf16 conversions (x, Wqkv, Wout) ----------------
#define XV4 524288     // (2*1024*1024)/4
#define WQV4 786432    // (3072*1024)/4
#define WOV4 262144    // (1024*1024)/4
#define TOTV4 (XV4 + WQV4 + WOV4)
__global__ __launch_bounds__(256) void conv_kernel(
    const float* __restrict__ x, const float* __restrict__ Wqkv,
    const float* __restrict__ Wout,
    __bf16* __restrict__ xb, __bf16* __restrict__ Wqkvb, __bf16* __restrict__ Woutb) {
  for (size_t i = (size_t)blockIdx.x * blockDim.x + threadIdx.x; i < TOTV4;
       i += (size_t)gridDim.x * blockDim.x) {
    const float4* src; __bf16* dst; size_t off;
    if (i < XV4)            { src = (const float4*)x;    dst = xb;    off = i; }
    else if (i < XV4+WQV4)  { src = (const float4*)Wqkv; dst = Wqkvb; off = i - XV4; }
    else                    { src = (const float4*)Wout; dst = Woutb; off = i - XV4 - WQV4; }
    float4 val = src[off];
    bf16x4 o = {(__bf16)val.x, (__bf16)val.y, (__bf16)val.z, (__bf16)val.w};
    *(bf16x4*)(dst + off * 4) = o;
  }
}

// ---------------- K0: importance (spike) + alpha (f32 — sign decision!) ----------------
__global__ __launch_bounds__(256) void imp_alpha_kernel(
    const float* __restrict__ x,
    const float* __restrict__ Wimp, const float* __restrict__ bimp,
    const float* __restrict__ Walpha, const float* __restrict__ balpha,
    const float* __restrict__ thr_p,
    float* __restrict__ spike, float* __restrict__ alpha) {
  int m = blockIdx.x;
  int tid = threadIdx.x;           // one float4 per thread (1024/4 = 256)
  const float4* xr = (const float4*)(x + (size_t)m * E_);
  float4 xv = xr[tid];
  float part[17];
  {
    float4 wv = ((const float4*)Wimp)[tid];
    part[16] = xv.x * wv.x + xv.y * wv.y + xv.z * wv.z + xv.w * wv.w;
  }
#pragma unroll
  for (int h = 0; h < 16; ++h) {
    float4 wv = ((const float4*)(Walpha + (size_t)h * E_))[tid];
    part[h] = xv.x * wv.x + xv.y * wv.y + xv.z * wv.z + xv.w * wv.w;
  }
  __shared__ float red[17][4];
  int lane = tid & 63, wv_ = tid >> 6;
#pragma unroll
  for (int i = 0; i < 17; ++i) {
    float v = part[i];
    for (int off = 32; off > 0; off >>= 1) v += __shfl_down(v, off, 64);
    if (lane == 0) red[i][wv_] = v;
  }
  __syncthreads();
  if (tid < 17) {
    float v = red[tid][0] + red[tid][1] + red[tid][2] + red[tid][3];
    if (tid == 16) {
      float z = v + bimp[0];
      float sig = 1.f / (1.f + expf(-z));
      spike[m] = (sig > thr_p[0]) ? 1.f : 0.f;
    } else {
      float z = v + balpha[tid];
      float a = 1.f / (1.f + expf(-z));
      int b = m >> 10, t = m & (T_ - 1);
      alpha[((size_t)(b * H_ + tid)) * T_ + t] = a;
    }
  }
}

// ---------------- K1: QKV GEMM — bf16 MFMA, 128x128 tile ----------------
__global__ __launch_bounds__(256) void qkv_gemm_kernel(
    const __bf16* __restrict__ A, const __bf16* __restrict__ Bm,
    const float* __restrict__ bias,
    __bf16* __restrict__ q, __bf16* __restrict__ k, __bf16* __restrict__ v) {
  __shared__ __bf16 As[128 * 32];
  __shared__ __bf16 Bs[128 * 32];
  const int K = E_;
  int tid = threadIdx.x;
  int w = tid >> 6, lane = tid & 63, lr = lane & 15, g = lane >> 4;
  int m0 = blockIdx.y * 128, n0 = blockIdx.x * 128;
  int wr = (w >> 1) * 64, wc = (w & 1) * 64;

  int task0 = tid, task1 = tid + 256;
  int r0s = task0 >> 2, c0s = task0 & 3;
  int r1s = task1 >> 2, c1s = task1 & 3;
  const __bf16* gA0 = A + (size_t)(m0 + r0s) * K + c0s * 8;
  const __bf16* gA1 = A + (size_t)(m0 + r1s) * K + c1s * 8;
  const __bf16* gB0 = Bm + (size_t)(n0 + r0s) * K + c0s * 8;
  const __bf16* gB1 = Bm + (size_t)(n0 + r1s) * K + c1s * 8;
  __bf16* lA0 = As + task0 * 8;
  __bf16* lA1 = As + task1 * 8;
  __bf16* lB0 = Bs + task0 * 8;
  __bf16* lB1 = Bs + task1 * 8;

  f32x4 acc[4][4];
#pragma unroll
  for (int i = 0; i < 4; ++i)
#pragma unroll
    for (int j = 0; j < 4; ++j) acc[i][j] = (f32x4){0.f, 0.f, 0.f, 0.f};

  for (int k0 = 0; k0 < K; k0 += 32) {
    gload_lds16(gA0, lA0); gload_lds16(gA1, lA1);
    gload_lds16(gB0, lB0); gload_lds16(gB1, lB1);
    gA0 += 32; gA1 += 32; gB0 += 32; gB1 += 32;
    __syncthreads();
    bf16x8 af[4], bf[4];
#pragma unroll
    for (int i = 0; i < 4; ++i) af[i] = *(bf16x8*)&As[(wr + i * 16 + lr) * 32 + g * 8];
#pragma unroll
    for (int j = 0; j < 4; ++j) bf[j] = *(bf16x8*)&Bs[(wc + j * 16 + lr) * 32 + g * 8];
#pragma unroll
    for (int i = 0; i < 4; ++i)
#pragma unroll
      for (int j = 0; j < 4; ++j)
        acc[i][j] = __builtin_amdgcn_mfma_f32_16x16x32_bf16(af[i], bf[j], acc[i][j], 0, 0, 0);
    __syncthreads();
  }

#pragma unroll
  for (int i = 0; i < 4; ++i) {
#pragma unroll
    for (int r = 0; r < 4; ++r) {
      int m = m0 + wr + i * 16 + g * 4 + r;
      int b = m >> 10, t = m & (T_ - 1);
#pragma unroll
      for (int j = 0; j < 4; ++j) {
        int n = n0 + wc + j * 16 + lr;
        float val = acc[i][j][r] + bias[n];
        int comp = n >> 10, h = (n >> 6) & 15, d = n & 63;
        __bf16* dst = (comp == 0) ? q : ((comp == 1) ? k : v);
        dst[(((size_t)(b * H_ + h)) * T_ + t) * 64 + d] = (__bf16)val;
      }
    }
  }
}

// ---------------- K2: hyperboloid scalars A,B,C per row ----------------
__global__ __launch_bounds__(256) void scal_kernel(
    const __bf16* __restrict__ q, const __bf16* __restrict__ k,
    const float* __restrict__ qk_scale_p,
    float* __restrict__ scalq, float* __restrict__ scalk) {
  int wid = blockIdx.x * 4 + (threadIdx.x >> 6);
  int lane = threadIdx.x & 63;
  int is_k = wid >> 15;
  int row = wid & 32767;
  const __bf16* src = (is_k ? k : q) + (size_t)row * 64;
  float u = (float)src[lane];
  float nsq = u * u;
#pragma unroll
  for (int off = 32; off > 0; off >>= 1) nsq += __shfl_xor(nsq, off, 64);
  float norm = fmaxf(sqrtf(nsq), 1e-12f);
  float ss = 1.5f / (1.f + expf(-qk_scale_p[0]));
  float row0 = __shfl(u, 0, 64);
  float un0 = row0 / norm * ss;
  float mink = ss * ss - 2.f * un0 * un0;
  float nu = sqrtf(fmaxf(mink, 1e-8f));
  float sc = sinhf(nu) / nu;
  float Bv = sc * ss / norm;
  float Av = sqrtf(1.f + sc * sc * (ss * ss - un0 * un0));
  float Cv = Bv * row0;
  if (lane == 0) {
    float* dst = is_k ? scalk : scalq;
    dst[row] = Av;
    dst[SPLANE + row] = Bv;
    dst[2 * SPLANE + row] = Cv;
  }
}

// ---------------- K3: quarter-split staged dual-geometry flash attention ----------------
// grid 1280 = 32 bh x 40 quarter-blocks; each block <= 4 s-tiles. LDS 24KB;
// natural VGPR (~88) allows 5 waves/SIMD -> 5 blocks/CU. NO forced
// launch_bounds occupancy (r9 lesson: (256,5) spilled to scratch, 82MB writes).
__global__ __launch_bounds__(256) void attn_kernel(
    const __bf16* __restrict__ q, const __bf16* __restrict__ k, const __bf16* __restrict__ v,
    const float* __restrict__ scalq, const float* __restrict__ scalk,
    const float* __restrict__ alpha, const float* __restrict__ log_k,
    __bf16* __restrict__ pacc, float* __restrict__ pml) {
  __shared__ __bf16 k_s[64 * 64];
  __shared__ __bf16 vt_s[64 * 64];
  __shared__ __bf16 p_s[64 * 64];

  int bid = blockIdx.x;
  int bh = ((bid & 7) << 2) | ((bid >> 3) & 3);  // 4 bh per XCD (L2 locality)
  int l = bid >> 5;                              // 0..39 quarter-slot
  int qt = 0, ii = 0;
#pragma unroll
  for (int u = 0; u < 16; ++u) {
    int offu = qoff(u);
    int nqu = (u >> 2) + 1;
    if (l >= offu && l < offu + nqu) { qt = u; ii = l - offu; }
  }
  int h = bh & 15;
  int t0 = qt * 64;
  int s_beg = ii * 4;
  int s_end = min(ii * 4 + 4, qt + 1);

  int tid = threadIdx.x;
  int w = tid >> 6, lane = tid & 63;
  int lr = lane & 15, g = lane >> 4;
  int trow = w * 16;
  const size_t base = (size_t)bh * T_ * 64;

  // Q A-fragments straight from global (L2-hot)
  const __bf16* qrow = q + base + (size_t)(t0 + trow + lr) * 64;
  bf16x8 aq0 = *(const bf16x8*)(qrow + g * 8);
  bf16x8 aq1 = *(const bf16x8*)(qrow + 32 + g * 8);

  float curv = log1pf(expf(log_k[h])) + 1e-6f;
  float hc = 0.69314718056f / curv;        // ln2/curv (log2-domain)
  const float ec = 0.18033688f;            // 0.125 * log2(e)
  int tg[4]; float al[4], Aq[4], Bq[4], Cq[4];
#pragma unroll
  for (int r = 0; r < 4; ++r) {
    tg[r] = t0 + trow + g * 4 + r;
    int rowi = (bh << 10) + tg[r];
    al[r] = alpha[(size_t)bh * T_ + tg[r]];
    Aq[r] = scalq[rowi];
    Bq[r] = scalq[SPLANE + rowi];
    Cq[r] = scalq[2 * SPLANE + rowi];
  }

  float m_r[4] = {-1e30f, -1e30f, -1e30f, -1e30f};
  float l_r[4] = {0.f, 0.f, 0.f, 0.f};
  f32x4 acc[4];
#pragma unroll
  for (int n = 0; n < 4; ++n) acc[n] = (f32x4){0.f, 0.f, 0.f, 0.f};

  // staging task decomposition
  int task0 = tid, task1 = tid + 256;
  int row0s = task0 >> 3, cj0 = task0 & 7;
  int row1s = task1 >> 3, cj1 = task1 & 7;
  int s2 = tid & 31, dc = tid >> 5;        // V: 2 s-rows x 8 d each

  for (int st = s_beg; st < s_end; ++st) {
    int s0 = st * 64;
    bool diag = (st == qt);
    __syncthreads();
    // ---- hoisted per-column scalars (issue early; off the dependent path) ----
    float akv[4], bkv[4], ckv[4];
#pragma unroll
    for (int j = 0; j < 4; ++j) {
      int coli = (bh << 10) + s0 + j * 16 + lr;
      akv[j] = scalk[coli];
      bkv[j] = scalk[SPLANE + coli];
      ckv[j] = scalk[2 * SPLANE + coli];
    }
    // ---- stage K (b128) and V^T (packed b32 pairs) ----
    {
      bf16x8 a0 = *(const bf16x8*)(k + base + (size_t)(s0 + row0s) * 64 + cj0 * 8);
      bf16x8 a1 = *(const bf16x8*)(k + base + (size_t)(s0 + row1s) * 64 + cj1 * 8);
      *(bf16x8*)ldsp(k_s, row0s, cj0 * 16) = a0;
      *(bf16x8*)ldsp(k_s, row1s, cj1 * 16) = a1;
      bf16x8 v0 = *(const bf16x8*)(v + base + (size_t)(s0 + 2 * s2) * 64 + dc * 8);
      bf16x8 v1 = *(const bf16x8*)(v + base + (size_t)(s0 + 2 * s2 + 1) * 64 + dc * 8);
#pragma unroll
      for (int i = 0; i < 8; ++i) {
        bf16x2 pr = {v0[i], v1[i]};
        *(bf16x2*)ldsp(vt_s, dc * 8 + i, s2 * 4) = pr;
      }
    }
    __syncthreads();

    // ---- per-j: euclid MFMA + scalar-hyper blend (causal only on diagonal) ----
    float pv[4][4];
    float pmax[4] = {-1e30f, -1e30f, -1e30f, -1e30f};
#pragma unroll
    for (int j = 0; j < 4; ++j) {
      if (diag && (s0 + j * 16 > t0 + trow + 15)) {   // wave-uniform full mask
#pragma unroll
        for (int r = 0; r < 4; ++r) pv[j][r] = -1e30f;
        continue;
      }
      bf16x8 bk0 = *(bf16x8*)ldsp(k_s, j * 16 + lr, g * 16);
      bf16x8 bk1 = *(bf16x8*)ldsp(k_s, j * 16 + lr, 64 + g * 16);
      f32x4 z = {0.f, 0.f, 0.f, 0.f};
      z = __builtin_amdgcn_mfma_f32_16x16x32_bf16(aq0, bk0, z, 0, 0, 0);
      f32x4 se = __builtin_amdgcn_mfma_f32_16x16x32_bf16(aq1, bk1, z, 0, 0, 0);
      int sg = s0 + j * 16 + lr;
#pragma unroll
      for (int r = 0; r < 4; ++r) {
        float dot = se[r];
        float sc_e = dot * ec;
        float md = fmaf(-Bq[r] * bkv[j], dot, fmaf(Aq[r], akv[j], Cq[r] * ckv[j]));
        md = fmaxf(md, 1.0f + 1e-6f);
        float l2 = __log2f(md + sqrtf(fmaf(md, md, -1.f)));  // acosh, log2 units
        float t = fmaf(l2 * l2, hc, sc_e);
        float s = fmaf(-al[r], t, sc_e);                      // (1-a)e - a*h
        if (diag && sg > tg[r]) s = -1e30f;
        pv[j][r] = s;
        pmax[r] = fmaxf(pmax[r], s);
      }
    }
    // ---- online softmax (log2 domain) ----
#pragma unroll
    for (int r = 0; r < 4; ++r) {
      float mx = pmax[r];
      mx = fmaxf(mx, __shfl_xor(mx, 1, 64));
      mx = fmaxf(mx, __shfl_xor(mx, 2, 64));
      mx = fmaxf(mx, __shfl_xor(mx, 4, 64));
      mx = fmaxf(mx, __shfl_xor(mx, 8, 64));
      float mn = fmaxf(m_r[r], mx);
      float fac = exp2f(m_r[r] - mn);
      m_r[r] = mn;
      float ls = 0.f;
#pragma unroll
      for (int j = 0; j < 4; ++j) { pv[j][r] = exp2f(pv[j][r] - mn); ls += pv[j][r]; }
      ls += __shfl_xor(ls, 1, 64);
      ls += __shfl_xor(ls, 2, 64);
      ls += __shfl_xor(ls, 4, 64);
      ls += __shfl_xor(ls, 8, 64);
      l_r[r] = l_r[r] * fac + ls;
#pragma unroll
      for (int n = 0; n < 4; ++n) acc[n][r] *= fac;
    }
    // ---- P transpose through wave-private p_s rows (no barrier needed) ----
#pragma unroll
    for (int j = 0; j < 4; ++j)
#pragma unroll
      for (int r = 0; r < 4; ++r)
        *(__bf16*)ldsp(p_s, trow + g * 4 + r, (j * 16 + lr) * 2) = (__bf16)pv[j][r];
    bf16x8 ap0 = *(bf16x8*)ldsp(p_s, trow + lr, g * 16);
    bf16x8 ap1 = *(bf16x8*)ldsp(p_s, trow + lr, 64 + g * 16);
#pragma unroll
    for (int n = 0; n < 4; ++n) {
      bf16x8 bv0 = *(bf16x8*)ldsp(vt_s, n * 16 + lr, g * 16);
      bf16x8 bv1 = *(bf16x8*)ldsp(vt_s, n * 16 + lr, 64 + g * 16);
      acc[n] = __builtin_amdgcn_mfma_f32_16x16x32_bf16(ap0, bv0, acc[n], 0, 0, 0);
      acc[n] = __builtin_amdgcn_mfma_f32_16x16x32_bf16(ap1, bv1, acc[n], 0, 0, 0);
    }
  }

  // ---- write partials (merge kernel combines nq quarters) ----
  int pidx = ((bh * 40 + qoff(qt) + ii) << 2) | w;
  __bf16* pa = pacc + (size_t)pidx * 1024;
#pragma unroll
  for (int n = 0; n < 4; ++n)
#pragma unroll
    for (int r = 0; r < 4; ++r)
      pa[(g * 4 + r) * 64 + n * 16 + lr] = (__bf16)acc[n][r];
  if (lr == 0) {
#pragma unroll
    for (int r = 0; r < 4; ++r) {
      pml[(size_t)pidx * 32 + g * 4 + r] = m_r[r];
      pml[(size_t)pidx * 32 + 16 + g * 4 + r] = l_r[r];
    }
  }
}

// ---------------- K3b: merge nq quarters + spike gate -> yw (bf16) ----------------
__global__ __launch_bounds__(256) void merge_kernel(
    const __bf16* __restrict__ pacc, const float* __restrict__ pml,
    const float* __restrict__ spike, __bf16* __restrict__ yw) {
  int tid = threadIdx.x;
  int w = tid >> 6, lane = tid & 63;
  int wid = blockIdx.x * 4 + w;          // 0..2047
  int bh = wid & 31;
  int qt16 = wid >> 5;                   // 0..63 (16-row tile)
  int b = bh >> 4, h = bh & 15;
  int qt = qt16 >> 2, wsub = qt16 & 3;
  int nq = (qt >> 2) + 1;
  int offq = qoff(qt);
  int pp[4];
#pragma unroll
  for (int i = 0; i < 4; ++i)
    pp[i] = ((bh * 40 + offq + min(i, nq - 1)) << 2) | wsub;

  for (int row = 0; row < 16; ++row) {
    float mm = -1e30f;
    float mv[4];
#pragma unroll
    for (int i = 0; i < 4; ++i) {
      mv[i] = (i < nq) ? pml[(size_t)pp[i] * 32 + row] : -1e30f;
      mm = fmaxf(mm, mv[i]);
    }
    float lsum = 0.f, val = 0.f;
#pragma unroll
    for (int i = 0; i < 4; ++i) {
      if (i < nq) {
        float f = exp2f(mv[i] - mm);
        lsum += pml[(size_t)pp[i] * 32 + 16 + row] * f;
        val += (float)pacc[(size_t)pp[i] * 1024 + row * 64 + lane] * f;
      }
    }
    int t = qt16 * 16 + row;
    float iv = spike[(size_t)b * T_ + t] / lsum;
    yw[(size_t)(b * T_ + t) * E_ + h * 64 + lane] = (__bf16)(val * iv);
  }
}

// ---------------- K4: output projection — bf16 MFMA, f32 out ----------------
__global__ __launch_bounds__(256) void out_gemm_kernel(
    const __bf16* __restrict__ A, const __bf16* __restrict__ Bm,
    const float* __restrict__ bias, float* __restrict__ outp) {
  __shared__ __bf16 As[128 * 32];
  __shared__ __bf16 Bs[128 * 32];
  const int K = E_;
  int tid = threadIdx.x;
  int w = tid >> 6, lane = tid & 63, lr = lane & 15, g = lane >> 4;
  int m0 = blockIdx.y * 128, n0 = blockIdx.x * 128;
  int wr = (w >> 1) * 64, wc = (w & 1) * 64;

  int task0 = tid, task1 = tid + 256;
  int r0s = task0 >> 2, c0s = task0 & 3;
  int r1s = task1 >> 2, c1s = task1 & 3;
  const __bf16* gA0 = A + (size_t)(m0 + r0s) * K + c0s * 8;
  const __bf16* gA1 = A + (size_t)(m0 + r1s) * K + c1s * 8;
  const __bf16* gB0 = Bm + (size_t)(n0 + r0s) * K + c0s * 8;
  const __bf16* gB1 = Bm + (size_t)(n0 + r1s) * K + c1s * 8;
  __bf16* lA0 = As + task0 * 8;
  __bf16* lA1 = As + task1 * 8;
  __bf16* lB0 = Bs + task0 * 8;
  __bf16* lB1 = Bs + task1 * 8;

  f32x4 acc[4][4];
#pragma unroll
  for (int i = 0; i < 4; ++i)
#pragma unroll
    for (int j = 0; j < 4; ++j) acc[i][j] = (f32x4){0.f, 0.f, 0.f, 0.f};

  for (int k0 = 0; k0 < K; k0 += 32) {
    gload_lds16(gA0, lA0); gload_lds16(gA1, lA1);
    gload_lds16(gB0, lB0); gload_lds16(gB1, lB1);
    gA0 += 32; gA1 += 32; gB0 += 32; gB1 += 32;
    __syncthreads();
    bf16x8 af[4], bf[4];
#pragma unroll
    for (int i = 0; i < 4; ++i) af[i] = *(bf16x8*)&As[(wr + i * 16 + lr) * 32 + g * 8];
#pragma unroll
    for (int j = 0; j < 4; ++j) bf[j] = *(bf16x8*)&Bs[(wc + j * 16 + lr) * 32 + g * 8];
#pragma unroll
    for (int i = 0; i < 4; ++i)
#pragma unroll
      for (int j = 0; j < 4; ++j)
        acc[i][j] = __builtin_amdgcn_mfma_f32_16x16x32_bf16(af[i], bf[j], acc[i][j], 0, 0, 0);
    __syncthreads();
  }

#pragma unroll
  for (int i = 0; i < 4; ++i) {
#pragma unroll
    for (int r = 0; r < 4; ++r) {
      int m = m0 + wr + i * 16 + g * 4 + r;
#pragma unroll
      for (int j = 0; j < 4; ++j) {
        int n = n0 + wc + j * 16 + lr;
        outp[(size_t)m * E_ + n] = acc[i][j][r] + bias[n];
      }
    }
  }
}

extern "C" void kernel_launch(void* const* d_in, const int* in_sizes, int n_in,
                              void* d_out, int out_size, void* d_ws, size_t ws_size,
                              hipStream_t stream) {
  const float* x      = (const float*)d_in[0];
  const float* Wqkv   = (const float*)d_in[1];
  const float* bqkv   = (const float*)d_in[2];
  const float* Wout   = (const float*)d_in[3];
  const float* bout   = (const float*)d_in[4];
  const float* Wimp   = (const float*)d_in[5];
  const float* bimp   = (const float*)d_in[6];
  const float* Walpha = (const float*)d_in[7];
  const float* balpha = (const float*)d_in[8];
  const float* thr    = (const float*)d_in[9];
  const float* log_k  = (const float*)d_in[10];
  const float* qk_sc  = (const float*)d_in[11];
  float* out = (float*)d_out;

  char* ws = (char*)d_ws;
  size_t off = 0;
  auto alloc = [&](size_t bytes) -> void* {
    void* p = (void*)(ws + off);
    off += (bytes + 255) & ~(size_t)255;
    return p;
  };
  const size_t qkv_elems = (size_t)B_ * H_ * T_ * D_;
  __bf16* xb    = (__bf16*)alloc((size_t)M_ * E_ * 2);      // dead after qkv_gemm
  __bf16* Wqkvb = (__bf16*)alloc((size_t)3 * E_ * E_ * 2);  // dead after qkv_gemm
  __bf16* Woutb = (__bf16*)alloc((size_t)E_ * E_ * 2);
  __bf16* q   = (__bf16*)alloc(qkv_elems * 2);
  __bf16* k   = (__bf16*)alloc(qkv_elems * 2);
  __bf16* v   = (__bf16*)alloc(qkv_elems * 2);
  __bf16* yw  = (__bf16*)alloc((size_t)M_ * E_ * 2);
  float* alphaw = (float*)alloc((size_t)B_ * H_ * T_ * sizeof(float));
  float* spikew = (float*)alloc((size_t)M_ * sizeof(float));
  float* pml    = (float*)alloc((size_t)5120 * 32 * sizeof(float));
  float* scalq  = (float*)alloc((size_t)3 * SPLANE * sizeof(float));
  float* scalk  = (float*)alloc((size_t)3 * SPLANE * sizeof(float));
  // pacc: 5120 partials x 1024 bf16 = 10,485,760 B == xb(4MB)+Wqkvb(6MB) alias
  __bf16* pacc = (__bf16*)ws;

  conv_kernel<<<1024, 256, 0, stream>>>(x, Wqkv, Wout, xb, Wqkvb, Woutb);
  imp_alpha_kernel<<<M_, 256, 0, stream>>>(x, Wimp, bimp, Walpha, balpha, thr,
                                           spikew, alphaw);
  qkv_gemm_kernel<<<dim3(24, 16), 256, 0, stream>>>(xb, Wqkvb, bqkv, q, k, v);
  scal_kernel<<<(2 * B_ * H_ * T_) / 4, 256, 0, stream>>>(q, k, qk_sc, scalq, scalk);
  attn_kernel<<<1280, 256, 0, stream>>>(q, k, v, scalq, scalk, alphaw, log_k,
                                        pacc, pml);
  merge_kernel<<<512, 256, 0, stream>>>(pacc, pml, spikew, yw);
  out_gemm_kernel<<<dim3(8, 16), 256, 0, stream>>>(yw, Woutb, bout, out);
}

// Round 11
// 155.509 us; speedup vs baseline: 1.4244x; 1.0503x over previous
//
#include <hip/hip_runtime.h>
#include <math.h>

#define B_ 2
#define T_ 1024
#define E_ 1024
#define H_ 16
#define D_ 64
#define M_ (B_*T_)
#define SPLANE 32768   // scal plane stride (32 bh * 1024 t)

typedef __bf16 bf16x8 __attribute__((ext_vector_type(8)));
typedef __bf16 bf16x4 __attribute__((ext_vector_type(4)));
typedef __bf16 bf16x2 __attribute__((ext_vector_type(2)));
typedef float f32x4 __attribute__((ext_vector_type(4)));

// swizzled LDS addressing: row-major [rows][128 bytes], byte ^= (row&7)<<4
__device__ __forceinline__ void* ldsp(__bf16* base, int row, int byte) {
  return (char*)base + row * 128 + (byte ^ ((row & 7) << 4));
}

__device__ __forceinline__ void gload_lds16(const void* g, void* l) {
  __builtin_amdgcn_global_load_lds((const __attribute__((address_space(1))) void*)g,
                                   (__attribute__((address_space(3))) void*)l, 16, 0, 0);
}

// quarter-layout helpers: nq(qt) = qt/4+1, off(qt) = qt + 2a(a-1) + a*(qt&3), a=qt>>2
__device__ __forceinline__ int qoff(int qt) {
  int a = qt >> 2, r = qt & 3;
  return qt + 2 * a * (a - 1) + a * r;
}

// ---------------- K0: fused prep — imp/alpha GEMVs + x->xb + W conversions ----------------
// blocks 0..2047: per-row x work (17 dots, spike/alpha, bf16 x copy)
// blocks 2048..3071: grid-stride conversion of Wqkv and Wout
#define WQV4 786432    // (3072*1024)/4
#define WOV4 262144    // (1024*1024)/4
__global__ __launch_bounds__(256) void prep_kernel(
    const float* __restrict__ x, const float* __restrict__ Wqkv,
    const float* __restrict__ Wout,
    const float* __restrict__ Wimp, const float* __restrict__ bimp,
    const float* __restrict__ Walpha, const float* __restrict__ balpha,
    const float* __restrict__ thr_p,
    __bf16* __restrict__ xb, __bf16* __restrict__ Wqkvb, __bf16* __restrict__ Woutb,
    float* __restrict__ spike, float* __restrict__ alpha) {
  int tid = threadIdx.x;
  if (blockIdx.x >= M_) {
    // ---- weight conversion path ----
    size_t cb = blockIdx.x - M_;
    for (size_t i = cb * 256 + tid; i < WQV4 + WOV4; i += (size_t)1024 * 256) {
      const float4* src; __bf16* dst; size_t off;
      if (i < WQV4) { src = (const float4*)Wqkv; dst = Wqkvb; off = i; }
      else          { src = (const float4*)Wout; dst = Woutb; off = i - WQV4; }
      float4 val = src[off];
      bf16x4 o = {(__bf16)val.x, (__bf16)val.y, (__bf16)val.z, (__bf16)val.w};
      *(bf16x4*)(dst + off * 4) = o;
    }
    return;
  }
  // ---- per-row x path ----
  int m = blockIdx.x;
  const float4* xr = (const float4*)(x + (size_t)m * E_);
  float4 xv = xr[tid];
  // bf16 copy of x (coalesced, one float4 -> bf16x4 per thread)
  bf16x4 xo = {(__bf16)xv.x, (__bf16)xv.y, (__bf16)xv.z, (__bf16)xv.w};
  *(bf16x4*)(xb + (size_t)m * E_ + tid * 4) = xo;
  float part[17];
  {
    float4 wv = ((const float4*)Wimp)[tid];
    part[16] = xv.x * wv.x + xv.y * wv.y + xv.z * wv.z + xv.w * wv.w;
  }
#pragma unroll
  for (int h = 0; h < 16; ++h) {
    float4 wv = ((const float4*)(Walpha + (size_t)h * E_))[tid];
    part[h] = xv.x * wv.x + xv.y * wv.y + xv.z * wv.z + xv.w * wv.w;
  }
  __shared__ float red[17][4];
  int lane = tid & 63, wv_ = tid >> 6;
#pragma unroll
  for (int i = 0; i < 17; ++i) {
    float v = part[i];
    for (int off = 32; off > 0; off >>= 1) v += __shfl_down(v, off, 64);
    if (lane == 0) red[i][wv_] = v;
  }
  __syncthreads();
  if (tid < 17) {
    float v = red[tid][0] + red[tid][1] + red[tid][2] + red[tid][3];
    if (tid == 16) {
      float z = v + bimp[0];
      float sig = 1.f / (1.f + expf(-z));
      spike[m] = (sig > thr_p[0]) ? 1.f : 0.f;
    } else {
      float z = v + balpha[tid];
      float a = 1.f / (1.f + expf(-z));
      int b = m >> 10, t = m & (T_ - 1);
      alpha[((size_t)(b * H_ + tid)) * T_ + t] = a;
    }
  }
}

// ---------------- K1: QKV GEMM — bf16 MFMA, 64x128 tile (768 blocks = 3/CU) ----------------
__global__ __launch_bounds__(256) void qkv_gemm_kernel(
    const __bf16* __restrict__ A, const __bf16* __restrict__ Bm,
    const float* __restrict__ bias,
    __bf16* __restrict__ q, __bf16* __restrict__ k, __bf16* __restrict__ v) {
  __shared__ __bf16 As[64 * 32];
  __shared__ __bf16 Bs[128 * 32];
  const int K = E_;
  int tid = threadIdx.x;
  int w = tid >> 6, lane = tid & 63, lr = lane & 15, g = lane >> 4;
  int m0 = blockIdx.y * 64, n0 = blockIdx.x * 128;
  int wr = (w >> 1) * 32, wc = (w & 1) * 64;

  int ra = tid >> 2, ca = (tid & 3) << 3;            // A: 1 chunk/thread
  int task1 = tid, task2 = tid + 256;                // B: 2 chunks/thread
  int rb1 = task1 >> 2, cb1 = (task1 & 3) << 3;
  int rb2 = task2 >> 2, cb2 = (task2 & 3) << 3;
  const __bf16* gA = A + (size_t)(m0 + ra) * K + ca;
  const __bf16* gB1 = Bm + (size_t)(n0 + rb1) * K + cb1;
  const __bf16* gB2 = Bm + (size_t)(n0 + rb2) * K + cb2;
  __bf16* lA = As + tid * 8;
  __bf16* lB1 = Bs + task1 * 8;
  __bf16* lB2 = Bs + task2 * 8;

  f32x4 acc[2][4];
#pragma unroll
  for (int i = 0; i < 2; ++i)
#pragma unroll
    for (int j = 0; j < 4; ++j) acc[i][j] = (f32x4){0.f, 0.f, 0.f, 0.f};

  for (int k0 = 0; k0 < K; k0 += 32) {
    gload_lds16(gA, lA);
    gload_lds16(gB1, lB1); gload_lds16(gB2, lB2);
    gA += 32; gB1 += 32; gB2 += 32;
    __syncthreads();
    bf16x8 af[2], bf[4];
#pragma unroll
    for (int i = 0; i < 2; ++i) af[i] = *(bf16x8*)&As[(wr + i * 16 + lr) * 32 + g * 8];
#pragma unroll
    for (int j = 0; j < 4; ++j) bf[j] = *(bf16x8*)&Bs[(wc + j * 16 + lr) * 32 + g * 8];
#pragma unroll
    for (int i = 0; i < 2; ++i)
#pragma unroll
      for (int j = 0; j < 4; ++j)
        acc[i][j] = __builtin_amdgcn_mfma_f32_16x16x32_bf16(af[i], bf[j], acc[i][j], 0, 0, 0);
    __syncthreads();
  }

#pragma unroll
  for (int i = 0; i < 2; ++i) {
#pragma unroll
    for (int r = 0; r < 4; ++r) {
      int m = m0 + wr + i * 16 + g * 4 + r;
      int b = m >> 10, t = m & (T_ - 1);
#pragma unroll
      for (int j = 0; j < 4; ++j) {
        int n = n0 + wc + j * 16 + lr;
        float val = acc[i][j][r] + bias[n];
        int comp = n >> 10, h = (n >> 6) & 15, d = n & 63;
        __bf16* dst = (comp == 0) ? q : ((comp == 1) ? k : v);
        dst[(((size_t)(b * H_ + h)) * T_ + t) * 64 + d] = (__bf16)val;
      }
    }
  }
}

// ---------------- K2: hyperboloid scalars A,B,C per row ----------------
__global__ __launch_bounds__(256) void scal_kernel(
    const __bf16* __restrict__ q, const __bf16* __restrict__ k,
    const float* __restrict__ qk_scale_p,
    float* __restrict__ scalq, float* __restrict__ scalk) {
  int wid = blockIdx.x * 4 + (threadIdx.x >> 6);
  int lane = threadIdx.x & 63;
  int is_k = wid >> 15;
  int row = wid & 32767;
  const __bf16* src = (is_k ? k : q) + (size_t)row * 64;
  float u = (float)src[lane];
  float nsq = u * u;
#pragma unroll
  for (int off = 32; off > 0; off >>= 1) nsq += __shfl_xor(nsq, off, 64);
  float norm = fmaxf(sqrtf(nsq), 1e-12f);
  float ss = 1.5f / (1.f + expf(-qk_scale_p[0]));
  float row0 = __shfl(u, 0, 64);
  float un0 = row0 / norm * ss;
  float mink = ss * ss - 2.f * un0 * un0;
  float nu = sqrtf(fmaxf(mink, 1e-8f));
  float sc = sinhf(nu) / nu;
  float Bv = sc * ss / norm;
  float Av = sqrtf(1.f + sc * sc * (ss * ss - un0 * un0));
  float Cv = Bv * row0;
  if (lane == 0) {
    float* dst = is_k ? scalk : scalq;
    dst[row] = Av;
    dst[SPLANE + row] = Bv;
    dst[2 * SPLANE + row] = Cv;
  }
}

// ---------------- K3: quarter-split staged dual-geometry flash attention ----------------
__global__ __launch_bounds__(256) void attn_kernel(
    const __bf16* __restrict__ q, const __bf16* __restrict__ k, const __bf16* __restrict__ v,
    const float* __restrict__ scalq, const float* __restrict__ scalk,
    const float* __restrict__ alpha, const float* __restrict__ log_k,
    __bf16* __restrict__ pacc, float* __restrict__ pml) {
  __shared__ __bf16 k_s[64 * 64];
  __shared__ __bf16 vt_s[64 * 64];
  __shared__ __bf16 p_s[64 * 64];

  int bid = blockIdx.x;
  int bh = ((bid & 7) << 2) | ((bid >> 3) & 3);  // 4 bh per XCD (L2 locality)
  int l = bid >> 5;                              // 0..39 quarter-slot
  int qt = 0, ii = 0;
#pragma unroll
  for (int u = 0; u < 16; ++u) {
    int offu = qoff(u);
    int nqu = (u >> 2) + 1;
    if (l >= offu && l < offu + nqu) { qt = u; ii = l - offu; }
  }
  int h = bh & 15;
  int t0 = qt * 64;
  int s_beg = ii * 4;
  int s_end = min(ii * 4 + 4, qt + 1);

  int tid = threadIdx.x;
  int w = tid >> 6, lane = tid & 63;
  int lr = lane & 15, g = lane >> 4;
  int trow = w * 16;
  const size_t base = (size_t)bh * T_ * 64;

  // Q A-fragments straight from global (L2-hot)
  const __bf16* qrow = q + base + (size_t)(t0 + trow + lr) * 64;
  bf16x8 aq0 = *(const bf16x8*)(qrow + g * 8);
  bf16x8 aq1 = *(const bf16x8*)(qrow + 32 + g * 8);

  float curv = log1pf(expf(log_k[h])) + 1e-6f;
  float hc = 0.69314718056f / curv;        // ln2/curv (log2-domain)
  const float ec = 0.18033688f;            // 0.125 * log2(e)
  int tg[4]; float al[4], Aq[4], Bq[4], Cq[4];
#pragma unroll
  for (int r = 0; r < 4; ++r) {
    tg[r] = t0 + trow + g * 4 + r;
    int rowi = (bh << 10) + tg[r];
    al[r] = alpha[(size_t)bh * T_ + tg[r]];
    Aq[r] = scalq[rowi];
    Bq[r] = scalq[SPLANE + rowi];
    Cq[r] = scalq[2 * SPLANE + rowi];
  }

  float m_r[4] = {-1e30f, -1e30f, -1e30f, -1e30f};
  float l_r[4] = {0.f, 0.f, 0.f, 0.f};
  f32x4 acc[4];
#pragma unroll
  for (int n = 0; n < 4; ++n) acc[n] = (f32x4){0.f, 0.f, 0.f, 0.f};

  // staging task decomposition
  int task0 = tid, task1 = tid + 256;
  int row0s = task0 >> 3, cj0 = task0 & 7;
  int row1s = task1 >> 3, cj1 = task1 & 7;
  int s2 = tid & 31, dc = tid >> 5;        // V: 2 s-rows x 8 d each

  for (int st = s_beg; st < s_end; ++st) {
    int s0 = st * 64;
    bool diag = (st == qt);
    __syncthreads();
    // ---- hoisted per-column scalars (issue early; off the dependent path) ----
    float akv[4], bkv[4], ckv[4];
#pragma unroll
    for (int j = 0; j < 4; ++j) {
      int coli = (bh << 10) + s0 + j * 16 + lr;
      akv[j] = scalk[coli];
      bkv[j] = scalk[SPLANE + coli];
      ckv[j] = scalk[2 * SPLANE + coli];
    }
    // ---- stage K (b128) and V^T (packed b32 pairs) ----
    {
      bf16x8 a0 = *(const bf16x8*)(k + base + (size_t)(s0 + row0s) * 64 + cj0 * 8);
      bf16x8 a1 = *(const bf16x8*)(k + base + (size_t)(s0 + row1s) * 64 + cj1 * 8);
      *(bf16x8*)ldsp(k_s, row0s, cj0 * 16) = a0;
      *(bf16x8*)ldsp(k_s, row1s, cj1 * 16) = a1;
      bf16x8 v0 = *(const bf16x8*)(v + base + (size_t)(s0 + 2 * s2) * 64 + dc * 8);
      bf16x8 v1 = *(const bf16x8*)(v + base + (size_t)(s0 + 2 * s2 + 1) * 64 + dc * 8);
#pragma unroll
      for (int i = 0; i < 8; ++i) {
        bf16x2 pr = {v0[i], v1[i]};
        *(bf16x2*)ldsp(vt_s, dc * 8 + i, s2 * 4) = pr;
      }
    }
    __syncthreads();

    // ---- per-j: euclid MFMA + scalar-hyper blend (causal only on diagonal) ----
    float pv[4][4];
    float pmax[4] = {-1e30f, -1e30f, -1e30f, -1e30f};
#pragma unroll
    for (int j = 0; j < 4; ++j) {
      if (diag && (s0 + j * 16 > t0 + trow + 15)) {   // wave-uniform full mask
#pragma unroll
        for (int r = 0; r < 4; ++r) pv[j][r] = -1e30f;
        continue;
      }
      bf16x8 bk0 = *(bf16x8*)ldsp(k_s, j * 16 + lr, g * 16);
      bf16x8 bk1 = *(bf16x8*)ldsp(k_s, j * 16 + lr, 64 + g * 16);
      f32x4 z = {0.f, 0.f, 0.f, 0.f};
      z = __builtin_amdgcn_mfma_f32_16x16x32_bf16(aq0, bk0, z, 0, 0, 0);
      f32x4 se = __builtin_amdgcn_mfma_f32_16x16x32_bf16(aq1, bk1, z, 0, 0, 0);
      int sg = s0 + j * 16 + lr;
#pragma unroll
      for (int r = 0; r < 4; ++r) {
        float dot = se[r];
        float sc_e = dot * ec;
        float md = fmaf(-Bq[r] * bkv[j], dot, fmaf(Aq[r], akv[j], Cq[r] * ckv[j]));
        md = fmaxf(md, 1.0f + 1e-6f);
        float l2 = __log2f(md + sqrtf(fmaf(md, md, -1.f)));  // acosh, log2 units
        float t = fmaf(l2 * l2, hc, sc_e);
        float s = fmaf(-al[r], t, sc_e);                      // (1-a)e - a*h
        if (diag && sg > tg[r]) s = -1e30f;
        pv[j][r] = s;
        pmax[r] = fmaxf(pmax[r], s);
      }
    }
    // ---- online softmax (log2 domain) ----
#pragma unroll
    for (int r = 0; r < 4; ++r) {
      float mx = pmax[r];
      mx = fmaxf(mx, __shfl_xor(mx, 1, 64));
      mx = fmaxf(mx, __shfl_xor(mx, 2, 64));
      mx = fmaxf(mx, __shfl_xor(mx, 4, 64));
      mx = fmaxf(mx, __shfl_xor(mx, 8, 64));
      float mn = fmaxf(m_r[r], mx);
      float fac = exp2f(m_r[r] - mn);
      m_r[r] = mn;
      float ls = 0.f;
#pragma unroll
      for (int j = 0; j < 4; ++j) { pv[j][r] = exp2f(pv[j][r] - mn); ls += pv[j][r]; }
      ls += __shfl_xor(ls, 1, 64);
      ls += __shfl_xor(ls, 2, 64);
      ls += __shfl_xor(ls, 4, 64);
      ls += __shfl_xor(ls, 8, 64);
      l_r[r] = l_r[r] * fac + ls;
#pragma unroll
      for (int n = 0; n < 4; ++n) acc[n][r] *= fac;
    }
    // ---- P transpose through wave-private p_s rows (no barrier needed) ----
#pragma unroll
    for (int j = 0; j < 4; ++j)
#pragma unroll
      for (int r = 0; r < 4; ++r)
        *(__bf16*)ldsp(p_s, trow + g * 4 + r, (j * 16 + lr) * 2) = (__bf16)pv[j][r];
    bf16x8 ap0 = *(bf16x8*)ldsp(p_s, trow + lr, g * 16);
    bf16x8 ap1 = *(bf16x8*)ldsp(p_s, trow + lr, 64 + g * 16);
#pragma unroll
    for (int n = 0; n < 4; ++n) {
      bf16x8 bv0 = *(bf16x8*)ldsp(vt_s, n * 16 + lr, g * 16);
      bf16x8 bv1 = *(bf16x8*)ldsp(vt_s, n * 16 + lr, 64 + g * 16);
      acc[n] = __builtin_amdgcn_mfma_f32_16x16x32_bf16(ap0, bv0, acc[n], 0, 0, 0);
      acc[n] = __builtin_amdgcn_mfma_f32_16x16x32_bf16(ap1, bv1, acc[n], 0, 0, 0);
    }
  }

  // ---- write partials (merge kernel combines nq quarters) ----
  int pidx = ((bh * 40 + qoff(qt) + ii) << 2) | w;
  __bf16* pa = pacc + (size_t)pidx * 1024;
#pragma unroll
  for (int n = 0; n < 4; ++n)
#pragma unroll
    for (int r = 0; r < 4; ++r)
      pa[(g * 4 + r) * 64 + n * 16 + lr] = (__bf16)acc[n][r];
  if (lr == 0) {
#pragma unroll
    for (int r = 0; r < 4; ++r) {
      pml[(size_t)pidx * 32 + g * 4 + r] = m_r[r];
      pml[(size_t)pidx * 32 + 16 + g * 4 + r] = l_r[r];
    }
  }
}

// ---------------- K3b: merge nq quarters + spike gate -> yw (bf16) ----------------
__global__ __launch_bounds__(256) void merge_kernel(
    const __bf16* __restrict__ pacc, const float* __restrict__ pml,
    const float* __restrict__ spike, __bf16* __restrict__ yw) {
  int tid = threadIdx.x;
  int w = tid >> 6, lane = tid & 63;
  int wid = blockIdx.x * 4 + w;          // 0..2047
  int bh = wid & 31;
  int qt16 = wid >> 5;                   // 0..63 (16-row tile)
  int b = bh >> 4, h = bh & 15;
  int qt = qt16 >> 2, wsub = qt16 & 3;
  int nq = (qt >> 2) + 1;
  int offq = qoff(qt);
  int pp[4];
#pragma unroll
  for (int i = 0; i < 4; ++i)
    pp[i] = ((bh * 40 + offq + min(i, nq - 1)) << 2) | wsub;

  for (int row = 0; row < 16; ++row) {
    float mm = -1e30f;
    float mv[4];
#pragma unroll
    for (int i = 0; i < 4; ++i) {
      mv[i] = (i < nq) ? pml[(size_t)pp[i] * 32 + row] : -1e30f;
      mm = fmaxf(mm, mv[i]);
    }
    float lsum = 0.f, val = 0.f;
#pragma unroll
    for (int i = 0; i < 4; ++i) {
      if (i < nq) {
        float f = exp2f(mv[i] - mm);
        lsum += pml[(size_t)pp[i] * 32 + 16 + row] * f;
        val += (float)pacc[(size_t)pp[i] * 1024 + row * 64 + lane] * f;
      }
    }
    int t = qt16 * 16 + row;
    float iv = spike[(size_t)b * T_ + t] / lsum;
    yw[(size_t)(b * T_ + t) * E_ + h * 64 + lane] = (__bf16)(val * iv);
  }
}

// ---------------- K4: output projection — bf16 MFMA, 64x128 tile (256 blocks) ----------------
__global__ __launch_bounds__(256) void out_gemm_kernel(
    const __bf16* __restrict__ A, const __bf16* __restrict__ Bm,
    const float* __restrict__ bias, float* __restrict__ outp) {
  __shared__ __bf16 As[64 * 32];
  __shared__ __bf16 Bs[128 * 32];
  const int K = E_;
  int tid = threadIdx.x;
  int w = tid >> 6, lane = tid & 63, lr = lane & 15, g = lane >> 4;
  int m0 = blockIdx.y * 64, n0 = blockIdx.x * 128;
  int wr = (w >> 1) * 32, wc = (w & 1) * 64;

  int ra = tid >> 2, ca = (tid & 3) << 3;
  int task1 = tid, task2 = tid + 256;
  int rb1 = task1 >> 2, cb1 = (task1 & 3) << 3;
  int rb2 = task2 >> 2, cb2 = (task2 & 3) << 3;
  const __bf16* gA = A + (size_t)(m0 + ra) * K + ca;
  const __bf16* gB1 = Bm + (size_t)(n0 + rb1) * K + cb1;
  const __bf16* gB2 = Bm + (size_t)(n0 + rb2) * K + cb2;
  __bf16* lA = As + tid * 8;
  __bf16* lB1 = Bs + task1 * 8;
  __bf16* lB2 = Bs + task2 * 8;

  f32x4 acc[2][4];
#pragma unroll
  for (int i = 0; i < 2; ++i)
#pragma unroll
    for (int j = 0; j < 4; ++j) acc[i][j] = (f32x4){0.f, 0.f, 0.f, 0.f};

  for (int k0 = 0; k0 < K; k0 += 32) {
    gload_lds16(gA, lA);
    gload_lds16(gB1, lB1); gload_lds16(gB2, lB2);
    gA += 32; gB1 += 32; gB2 += 32;
    __syncthreads();
    bf16x8 af[2], bf[4];
#pragma unroll
    for (int i = 0; i < 2; ++i) af[i] = *(bf16x8*)&As[(wr + i * 16 + lr) * 32 + g * 8];
#pragma unroll
    for (int j = 0; j < 4; ++j) bf[j] = *(bf16x8*)&Bs[(wc + j * 16 + lr) * 32 + g * 8];
#pragma unroll
    for (int i = 0; i < 2; ++i)
#pragma unroll
      for (int j = 0; j < 4; ++j)
        acc[i][j] = __builtin_amdgcn_mfma_f32_16x16x32_bf16(af[i], bf[j], acc[i][j], 0, 0, 0);
    __syncthreads();
  }

#pragma unroll
  for (int i = 0; i < 2; ++i) {
#pragma unroll
    for (int r = 0; r < 4; ++r) {
      int m = m0 + wr + i * 16 + g * 4 + r;
#pragma unroll
      for (int j = 0; j < 4; ++j) {
        int n = n0 + wc + j * 16 + lr;
        outp[(size_t)m * E_ + n] = acc[i][j][r] + bias[n];
      }
    }
  }
}

extern "C" void kernel_launch(void* const* d_in, const int* in_sizes, int n_in,
                              void* d_out, int out_size, void* d_ws, size_t ws_size,
                              hipStream_t stream) {
  const float* x      = (const float*)d_in[0];
  const float* Wqkv   = (const float*)d_in[1];
  const float* bqkv   = (const float*)d_in[2];
  const float* Wout   = (const float*)d_in[3];
  const float* bout   = (const float*)d_in[4];
  const float* Wimp   = (const float*)d_in[5];
  const float* bimp   = (const float*)d_in[6];
  const float* Walpha = (const float*)d_in[7];
  const float* balpha = (const float*)d_in[8];
  const float* thr    = (const float*)d_in[9];
  const float* log_k  = (const float*)d_in[10];
  const float* qk_sc  = (const float*)d_in[11];
  float* out = (float*)d_out;

  char* ws = (char*)d_ws;
  size_t off = 0;
  auto alloc = [&](size_t bytes) -> void* {
    void* p = (void*)(ws + off);
    off += (bytes + 255) & ~(size_t)255;
    return p;
  };
  const size_t qkv_elems = (size_t)B_ * H_ * T_ * D_;
  __bf16* xb    = (__bf16*)alloc((size_t)M_ * E_ * 2);      // dead after qkv_gemm
  __bf16* Wqkvb = (__bf16*)alloc((size_t)3 * E_ * E_ * 2);  // dead after qkv_gemm
  __bf16* Woutb = (__bf16*)alloc((size_t)E_ * E_ * 2);
  __bf16* q   = (__bf16*)alloc(qkv_elems * 2);
  __bf16* k   = (__bf16*)alloc(qkv_elems * 2);
  __bf16* v   = (__bf16*)alloc(qkv_elems * 2);
  __bf16* yw  = (__bf16*)alloc((size_t)M_ * E_ * 2);
  float* alphaw = (float*)alloc((size_t)B_ * H_ * T_ * sizeof(float));
  float* spikew = (float*)alloc((size_t)M_ * sizeof(float));
  float* pml    = (float*)alloc((size_t)5120 * 32 * sizeof(float));
  float* scalq  = (float*)alloc((size_t)3 * SPLANE * sizeof(float));
  float* scalk  = (float*)alloc((size_t)3 * SPLANE * sizeof(float));
  // pacc: 5120 partials x 1024 bf16 = 10,485,760 B == xb(4MB)+Wqkvb(6MB) alias
  __bf16* pacc = (__bf16*)ws;

  prep_kernel<<<M_ + 1024, 256, 0, stream>>>(x, Wqkv, Wout, Wimp, bimp,
                                             Walpha, balpha, thr,
                                             xb, Wqkvb, Woutb, spikew, alphaw);
  qkv_gemm_kernel<<<dim3(24, 32), 256, 0, stream>>>(xb, Wqkvb, bqkv, q, k, v);
  scal_kernel<<<(2 * B_ * H_ * T_) / 4, 256, 0, stream>>>(q, k, qk_sc, scalq, scalk);
  attn_kernel<<<1280, 256, 0, stream>>>(q, k, v, scalq, scalk, alphaw, log_k,
                                        pacc, pml);
  merge_kernel<<<512, 256, 0, stream>>>(pacc, pml, spikew, yw);
  out_gemm_kernel<<<dim3(8, 32), 256, 0, stream>>>(yw, Woutb, bout, out);
}